// Round 3
// baseline (609.703 us; speedup 1.0000x reference)
//
#include <hip/hip_runtime.h>
#include <hip/hip_bf16.h>
#include <cstdint>
#include <cstddef>

#define D_DIM 2048
#define S_SEQ 8192

typedef __attribute__((ext_vector_type(8))) short bf16x8;
typedef __attribute__((ext_vector_type(4))) float f32x4;

#define GAS __attribute__((address_space(1)))
#define LAS __attribute__((address_space(3)))

__device__ inline unsigned short f2b(float f) {
    __hip_bfloat16 h = __float2bfloat16(f);
    return __builtin_bit_cast(unsigned short, h);
}
__device__ inline float b2f(unsigned short u) {
    return __bfloat162float(__builtin_bit_cast(__hip_bfloat16, u));
}

// async global -> LDS, 16B per lane, LDS dest = wave-uniform base + lane*16
__device__ inline void gload_lds16(const unsigned short* g, unsigned short* l) {
    __builtin_amdgcn_global_load_lds((const GAS void*)g, (LAS void*)l, 16, 0, 0);
}

// ---------------- cast fp32 -> bf16 (vectorized) ----------------
__global__ __launch_bounds__(256)
void cast_f32_to_bf16(const float* __restrict__ in, unsigned short* __restrict__ out, int n4) {
    int stride = gridDim.x * blockDim.x;
    for (int i = blockIdx.x * blockDim.x + threadIdx.x; i < n4; i += stride) {
        float4 v = reinterpret_cast<const float4*>(in)[i];
        ushort4 o;
        o.x = f2b(v.x); o.y = f2b(v.y); o.z = f2b(v.z); o.w = f2b(v.w);
        reinterpret_cast<ushort4*>(out)[i] = o;
    }
}

// ---------------- GEMM: out[m,n] = sum_k A[m,k] * W[n,k] ----------------
// m97 structure: 128x128 tile, BK=32, 4 waves (2x2), global_load_lds width-16
// staging into LINEAR LDS (required by global_load_lds), 2-barrier K-loop.
// MODE 0: store bf16. MODE 2: store fp32.
template<int MODE>
__global__ __launch_bounds__(256)
void gemm_bt(const unsigned short* __restrict__ A,
             const unsigned short* __restrict__ W,
             void* __restrict__ out,
             int M, int N, int K)
{
    __shared__ unsigned short As[128 * 32];
    __shared__ unsigned short Ws[128 * 32];

    const int t    = threadIdx.x;
    const int lane = t & 63;
    const int wave = t >> 6;
    const int wr   = wave >> 1;   // 0..1
    const int wc   = wave & 1;    // 0..1

    const int row0 = blockIdx.x * 128;
    const int col0 = blockIdx.y * 128;

    // staging source mapping: lane l covers row (l>>2), elem col (l&3)*8 of a
    // 16-row x 32-col (1 KiB) slab; LDS dest is slab base + lane*16B (linear).
    const int srow = lane >> 2;
    const int scol = (lane & 3) << 3;

    f32x4 acc[4][4] = {};

    const int rl = lane & 15;
    const int kg = (lane >> 4) * 8;

    for (int k0 = 0; k0 < K; k0 += 32) {
        #pragma unroll
        for (int j = 0; j < 2; ++j) {
            const int rbase = wave * 32 + j * 16;   // wave-uniform
            gload_lds16(&A[(size_t)(row0 + rbase + srow) * K + k0 + scol],
                        &As[rbase * 32]);
            gload_lds16(&W[(size_t)(col0 + rbase + srow) * K + k0 + scol],
                        &Ws[rbase * 32]);
        }
        __syncthreads();   // drains vmcnt(0): staged data visible

        bf16x8 a[4], b[4];
        #pragma unroll
        for (int m = 0; m < 4; ++m)
            a[m] = *reinterpret_cast<const bf16x8*>(&As[(wr * 64 + m * 16 + rl) * 32 + kg]);
        #pragma unroll
        for (int n = 0; n < 4; ++n)
            b[n] = *reinterpret_cast<const bf16x8*>(&Ws[(wc * 64 + n * 16 + rl) * 32 + kg]);

        #pragma unroll
        for (int m = 0; m < 4; ++m)
            #pragma unroll
            for (int n = 0; n < 4; ++n)
                acc[m][n] = __builtin_amdgcn_mfma_f32_16x16x32_bf16(a[m], b[n], acc[m][n], 0, 0, 0);

        __syncthreads();   // protect LDS from next iteration's staging
    }

    // C/D layout (m89-verified): col = lane&15, row = (lane>>4)*4 + reg
    const int cr = (lane >> 4) * 4;
    const int cc = lane & 15;
    #pragma unroll
    for (int m = 0; m < 4; ++m) {
        #pragma unroll
        for (int n = 0; n < 4; ++n) {
            int gr = row0 + wr * 64 + m * 16 + cr;
            int gc = col0 + wc * 64 + n * 16 + cc;
            #pragma unroll
            for (int r = 0; r < 4; ++r) {
                size_t off = (size_t)(gr + r) * N + gc;
                float v = acc[m][n][r];
                if (MODE == 0) {
                    ((unsigned short*)out)[off] = f2b(v);
                } else {
                    ((float*)out)[off] = v;
                }
            }
        }
    }
}

// ---------------- depthwise causal conv (K=3) + both gates, fused ----------
// Bx[s,d] = B[s,d] * xp[s,d] computed on the fly (rolling registers).
// y[s,d]  = C[s,d] * ( w0*Bx[s-2,d] + w1*Bx[s-1,d] + w2*Bx[s,d] )
// Bx[-1,d] = state[d,1], Bx[-2,d] = state[d,0]
#define CONV_CHUNK 8
__global__ __launch_bounds__(256)
void conv_gate(const unsigned short* __restrict__ Bp,
               const unsigned short* __restrict__ XPp,
               const unsigned short* __restrict__ Cp,
               const float* __restrict__ conv_w,
               const float* __restrict__ state,
               unsigned short* __restrict__ y)
{
    const int s0 = blockIdx.x * CONV_CHUNK;
    const int d0 = threadIdx.x << 3;    // 8 channels per thread

    float w0[8], w1[8], w2[8];
    #pragma unroll
    for (int j = 0; j < 8; ++j) {
        int d = d0 + j;
        w0[j] = conv_w[d * 3 + 0];
        w1[j] = conv_w[d * 3 + 1];
        w2[j] = conv_w[d * 3 + 2];
    }

    float p1[8], p2[8];   // Bx[s-1], Bx[s-2]
    if (s0 >= 2) {
        bf16x8 b2v  = *reinterpret_cast<const bf16x8*>(&Bp [(size_t)(s0 - 2) * D_DIM + d0]);
        bf16x8 x2v  = *reinterpret_cast<const bf16x8*>(&XPp[(size_t)(s0 - 2) * D_DIM + d0]);
        bf16x8 b1v  = *reinterpret_cast<const bf16x8*>(&Bp [(size_t)(s0 - 1) * D_DIM + d0]);
        bf16x8 x1v  = *reinterpret_cast<const bf16x8*>(&XPp[(size_t)(s0 - 1) * D_DIM + d0]);
        #pragma unroll
        for (int j = 0; j < 8; ++j) {
            p2[j] = b2f((unsigned short)b2v[j]) * b2f((unsigned short)x2v[j]);
            p1[j] = b2f((unsigned short)b1v[j]) * b2f((unsigned short)x1v[j]);
        }
    } else {  // s0 == 0
        #pragma unroll
        for (int j = 0; j < 8; ++j) {
            p2[j] = state[(d0 + j) * 2 + 0];
            p1[j] = state[(d0 + j) * 2 + 1];
        }
    }

    for (int s = s0; s < s0 + CONV_CHUNK; ++s) {
        bf16x8 bv = *reinterpret_cast<const bf16x8*>(&Bp [(size_t)s * D_DIM + d0]);
        bf16x8 xv = *reinterpret_cast<const bf16x8*>(&XPp[(size_t)s * D_DIM + d0]);
        bf16x8 cv = *reinterpret_cast<const bf16x8*>(&Cp [(size_t)s * D_DIM + d0]);
        bf16x8 o;
        #pragma unroll
        for (int j = 0; j < 8; ++j) {
            float cur = b2f((unsigned short)bv[j]) * b2f((unsigned short)xv[j]);
            float co  = w0[j] * p2[j] + w1[j] * p1[j] + w2[j] * cur;
            o[j] = (short)f2b(b2f((unsigned short)cv[j]) * co);
            p2[j] = p1[j];
            p1[j] = cur;
        }
        *reinterpret_cast<bf16x8*>(&y[(size_t)s * D_DIM + d0]) = o;
    }
}

// ---------------- launch ----------------
extern "C" void kernel_launch(void* const* d_in, const int* in_sizes, int n_in,
                              void* d_out, int out_size, void* d_ws, size_t ws_size,
                              hipStream_t stream) {
    const float* x          = (const float*)d_in[0];
    const float* B_w        = (const float*)d_in[1];
    const float* C_w        = (const float*)d_in[2];
    const float* x_w        = (const float*)d_in[3];
    const float* out_w      = (const float*)d_in[4];
    const float* conv_w     = (const float*)d_in[5];
    const float* conv_state = (const float*)d_in[6];

    const size_t SD = (size_t)S_SEQ * D_DIM;   // 16,777,216
    const size_t DD = (size_t)D_DIM * D_DIM;   // 4,194,304

    unsigned short* ws   = (unsigned short*)d_ws;
    unsigned short* xb   = ws;            // SD  (x bf16; reused as y after proj GEMMs)
    unsigned short* bwb  = xb + SD;       // DD
    unsigned short* cwb  = bwb + DD;      // DD
    unsigned short* xwb  = cwb + DD;      // DD
    unsigned short* owb  = xwb + DD;      // DD
    unsigned short* bx   = owb + DD;      // SD  (B projection)
    unsigned short* cbuf = bx + SD;       // SD  (C projection)
    unsigned short* xpb  = (unsigned short*)d_out; // SD shorts in SD-float buffer:
                                                   // scratch for xp, consumed before final GEMM
    unsigned short* yb   = xb;            // reuse x's slot after last x-consumer
    // ws use: 3*SD + 4*DD shorts = ~134 MB (same footprint as round 1)

    cast_f32_to_bf16<<<2048, 256, 0, stream>>>(x,     xb,  (int)(SD / 4));
    cast_f32_to_bf16<<<1024, 256, 0, stream>>>(B_w,   bwb, (int)(DD / 4));
    cast_f32_to_bf16<<<1024, 256, 0, stream>>>(C_w,   cwb, (int)(DD / 4));
    cast_f32_to_bf16<<<1024, 256, 0, stream>>>(x_w,   xwb, (int)(DD / 4));
    cast_f32_to_bf16<<<1024, 256, 0, stream>>>(out_w, owb, (int)(DD / 4));

    dim3 grid(S_SEQ / 128, D_DIM / 128);   // 64 x 16
    // B  = x @ B_w^T
    gemm_bt<0><<<grid, 256, 0, stream>>>(xb, bwb, bx,   S_SEQ, D_DIM, D_DIM);
    // xp = x @ x_w^T  (into d_out scratch)
    gemm_bt<0><<<grid, 256, 0, stream>>>(xb, xwb, xpb,  S_SEQ, D_DIM, D_DIM);
    // C  = x @ C_w^T
    gemm_bt<0><<<grid, 256, 0, stream>>>(xb, cwb, cbuf, S_SEQ, D_DIM, D_DIM);

    // y = C * conv(B .* xp)   (overwrites xb)
    conv_gate<<<S_SEQ / CONV_CHUNK, 256, 0, stream>>>(bx, xpb, cbuf, conv_w, conv_state, yb);

    // out = y @ out_w^T   (fp32, overwrites the xp scratch region)
    gemm_bt<2><<<grid, 256, 0, stream>>>(yb, owb, d_out, S_SEQ, D_DIM, D_DIM);
}

// Round 4
// 456.457 us; speedup vs baseline: 1.3357x; 1.3357x over previous
//
#include <hip/hip_runtime.h>
#include <hip/hip_bf16.h>
#include <cstdint>
#include <cstddef>

#define D_DIM 2048
#define S_SEQ 8192

typedef __attribute__((ext_vector_type(8))) short bf16x8;
typedef __attribute__((ext_vector_type(4))) float f32x4;

#define GAS __attribute__((address_space(1)))
#define LAS __attribute__((address_space(3)))

__device__ inline unsigned short f2b(float f) {
    __hip_bfloat16 h = __float2bfloat16(f);
    return __builtin_bit_cast(unsigned short, h);
}
__device__ inline float b2f(unsigned short u) {
    return __bfloat162float(__builtin_bit_cast(__hip_bfloat16, u));
}

// async global -> LDS, 16B per lane, LDS dest = wave-uniform base + lane*16
__device__ inline void gload_lds16(const unsigned short* g, unsigned short* l) {
    __builtin_amdgcn_global_load_lds((const GAS void*)g, (LAS void*)l, 16, 0, 0);
}

// ---------------- casts fp32 -> bf16 (vectorized) ----------------
__global__ __launch_bounds__(256)
void cast_f32_to_bf16(const float* __restrict__ in, unsigned short* __restrict__ out, int n4) {
    int stride = gridDim.x * blockDim.x;
    for (int i = blockIdx.x * blockDim.x + threadIdx.x; i < n4; i += stride) {
        float4 v = reinterpret_cast<const float4*>(in)[i];
        ushort4 o;
        o.x = f2b(v.x); o.y = f2b(v.y); o.z = f2b(v.z); o.w = f2b(v.w);
        reinterpret_cast<ushort4*>(out)[i] = o;
    }
}

// 4 weight matrices in one launch (dst regions contiguous)
__global__ __launch_bounds__(256)
void cast4_f32_to_bf16(const float* __restrict__ s0, const float* __restrict__ s1,
                       const float* __restrict__ s2, const float* __restrict__ s3,
                       unsigned short* __restrict__ out, int n4_each) {
    const float* srcs[4] = {s0, s1, s2, s3};
    const float* in = srcs[blockIdx.y];
    unsigned short* o = out + (size_t)blockIdx.y * (size_t)n4_each * 4;
    int stride = gridDim.x * blockDim.x;
    for (int i = blockIdx.x * blockDim.x + threadIdx.x; i < n4_each; i += stride) {
        float4 v = reinterpret_cast<const float4*>(in)[i];
        ushort4 u;
        u.x = f2b(v.x); u.y = f2b(v.y); u.z = f2b(v.z); u.w = f2b(v.w);
        reinterpret_cast<ushort4*>(o)[i] = u;
    }
}

// ---------------- GEMM: out[m,n] = sum_k A[m,k] * W[n,k] ----------------
// 256x256 tile, BK=32, 8 waves (2M x 4N), 512 threads.
// 4-slot LDS ring (128 KiB dynamic), global_load_lds width-16 staging 3 tiles
// ahead, ONE raw s_barrier per K-tile, counted s_waitcnt vmcnt(8) (never 0 in
// steady state). Source-side XOR swizzle (chunk ^= (row>>1)&3) + same XOR on
// ds_read -> 2-way (free) bank access. MODE 0: bf16 out, MODE 2: fp32 out.
#define BK 32
#define SLOT (256 * BK)          // elems per operand per slot (8192 = 16 KiB)
#define NSLOT 4
#define GEMM_LDS_BYTES (NSLOT * 2 * SLOT * 2)   // 131072

template<int MODE>
__global__ __launch_bounds__(512, 2)
void gemm_bt(const unsigned short* __restrict__ A,
             const unsigned short* __restrict__ W,
             void* __restrict__ out,
             int M, int N, int K)
{
    extern __shared__ unsigned short lds[];

    const int tid  = threadIdx.x;
    const int lane = tid & 63;
    const int wave = tid >> 6;        // 0..7
    const int wr   = wave >> 2;       // 0..1  (M halves of the tile)
    const int wc   = wave & 3;        // 0..3  (N quarters)

    // XCD-aware bijective swizzle (nwg = 256, divisible by 8)
    const int nwg = gridDim.x;
    const int bid = blockIdx.x;
    const int per = nwg >> 3;
    const int wg  = (bid & 7) * per + (bid >> 3);
    const int nbn = N >> 8;                     // blocks along N
    const int row0 = (wg / nbn) * 256;
    const int col0 = (wg % nbn) * 256;

    const int srow   = lane >> 2;     // 0..15 within a 16-row staging slab
    const int schunk = lane & 3;      // 16B chunk 0..3

    // stage one operand K-tile (256 rows x 32 cols) : 2 gload_lds per thread.
    // global source pre-swizzled so linear LDS + swizzled read are consistent.
    auto stage = [&](const unsigned short* G, int grow0, int k0, unsigned short* dst) {
        #pragma unroll
        for (int j = 0; j < 2; ++j) {
            const int R   = wave * 32 + j * 16;        // wave-uniform slab base row
            const int row = R + srow;
            const int c   = schunk ^ ((row >> 1) & 3); // inverse swizzle on source
            gload_lds16(&G[(size_t)(grow0 + row) * K + k0 + c * 8], dst + R * BK);
        }
    };

    const int NT = K / BK;   // 64

    // prologue: stage tiles 0,1,2 (12 loads/thread outstanding)
    for (int pt = 0; pt < 3; ++pt) {
        unsigned short* sb = lds + (pt & 3) * (2 * SLOT);
        stage(A, row0, pt * BK, sb);
        stage(W, col0, pt * BK, sb + SLOT);
    }

    f32x4 acc[8][4] = {};

    const int rl = lane & 15;
    const int ck = lane >> 4;         // k-chunk 0..3 of the fragment

    for (int t = 0; t < NT; ++t) {
        // Boundary: tile t's 4 loads are the oldest outstanding.
        // Outstanding = tiles t, t+1, t+2 (12 loads) steady state -> vmcnt(8).
        // lgkmcnt(0) drains this wave's ds_reads of slot (t-1)&3 BEFORE the
        // barrier, so staging tile t+3 into that slot after the barrier is safe.
        if (t < NT - 2) {
            asm volatile("s_waitcnt vmcnt(8) lgkmcnt(0)" ::: "memory");
        } else if (t == NT - 2) {
            asm volatile("s_waitcnt vmcnt(4) lgkmcnt(0)" ::: "memory");
        } else {
            asm volatile("s_waitcnt vmcnt(0) lgkmcnt(0)" ::: "memory");
        }
        __builtin_amdgcn_s_barrier();

        unsigned short* sb = lds + (t & 3) * (2 * SLOT);
        const unsigned short* Ab = sb;
        const unsigned short* Bb = sb + SLOT;

        // phase 0: stage A of tile t+3; read B n0..3 + A m0..3; 16 MFMA
        if (t + 3 < NT) {
            unsigned short* pb = lds + ((t + 3) & 3) * (2 * SLOT);
            stage(A, row0, (t + 3) * BK, pb);
        }

        bf16x8 b[4], a[4];
        #pragma unroll
        for (int n = 0; n < 4; ++n) {
            const int rowB = wc * 64 + n * 16 + rl;
            const int ph   = ck ^ ((rowB >> 1) & 3);
            b[n] = *reinterpret_cast<const bf16x8*>(&Bb[rowB * BK + ph * 8]);
        }
        #pragma unroll
        for (int m = 0; m < 4; ++m) {
            const int rowA = wr * 128 + m * 16 + rl;
            const int ph   = ck ^ ((rowA >> 1) & 3);
            a[m] = *reinterpret_cast<const bf16x8*>(&Ab[rowA * BK + ph * 8]);
        }

        __builtin_amdgcn_s_setprio(1);
        #pragma unroll
        for (int m = 0; m < 4; ++m)
            #pragma unroll
            for (int n = 0; n < 4; ++n)
                acc[m][n] = __builtin_amdgcn_mfma_f32_16x16x32_bf16(a[m], b[n], acc[m][n], 0, 0, 0);
        __builtin_amdgcn_s_setprio(0);

        // phase 1: stage B of tile t+3; read A m4..7; 16 MFMA
        if (t + 3 < NT) {
            unsigned short* pb = lds + ((t + 3) & 3) * (2 * SLOT);
            stage(W, col0, (t + 3) * BK, pb + SLOT);
        }

        #pragma unroll
        for (int m = 0; m < 4; ++m) {
            const int rowA = wr * 128 + 64 + m * 16 + rl;
            const int ph   = ck ^ ((rowA >> 1) & 3);
            a[m] = *reinterpret_cast<const bf16x8*>(&Ab[rowA * BK + ph * 8]);
        }
        __builtin_amdgcn_s_setprio(1);
        #pragma unroll
        for (int m = 0; m < 4; ++m)
            #pragma unroll
            for (int n = 0; n < 4; ++n)
                acc[4 + m][n] = __builtin_amdgcn_mfma_f32_16x16x32_bf16(a[m], b[n], acc[4 + m][n], 0, 0, 0);
        __builtin_amdgcn_s_setprio(0);
    }

    // C/D layout (m89-verified): col = lane&15, row = (lane>>4)*4 + reg
    const int cr = (lane >> 4) * 4;
    const int cc = lane & 15;
    #pragma unroll
    for (int m = 0; m < 8; ++m) {
        #pragma unroll
        for (int n = 0; n < 4; ++n) {
            const int gr = row0 + wr * 128 + m * 16 + cr;
            const int gc = col0 + wc * 64 + n * 16 + cc;
            #pragma unroll
            for (int r = 0; r < 4; ++r) {
                size_t off = (size_t)(gr + r) * N + gc;
                float v = acc[m][n][r];
                if (MODE == 0) {
                    ((unsigned short*)out)[off] = f2b(v);
                } else {
                    ((float*)out)[off] = v;
                }
            }
        }
    }
}

// ---------------- depthwise causal conv (K=3) + both gates, fused ----------
// Bx[s,d] = B[s,d]*xp[s,d] on the fly; y = C * (w0*Bx[s-2]+w1*Bx[s-1]+w2*Bx[s])
#define CONV_CHUNK 8
__global__ __launch_bounds__(256)
void conv_gate(const unsigned short* __restrict__ Bp,
               const unsigned short* __restrict__ XPp,
               const unsigned short* __restrict__ Cp,
               const float* __restrict__ conv_w,
               const float* __restrict__ state,
               unsigned short* __restrict__ y)
{
    const int s0 = blockIdx.x * CONV_CHUNK;
    const int d0 = threadIdx.x << 3;

    float w0[8], w1[8], w2[8];
    #pragma unroll
    for (int j = 0; j < 8; ++j) {
        int d = d0 + j;
        w0[j] = conv_w[d * 3 + 0];
        w1[j] = conv_w[d * 3 + 1];
        w2[j] = conv_w[d * 3 + 2];
    }

    float p1[8], p2[8];
    if (s0 >= 2) {
        bf16x8 b2v = *reinterpret_cast<const bf16x8*>(&Bp [(size_t)(s0 - 2) * D_DIM + d0]);
        bf16x8 x2v = *reinterpret_cast<const bf16x8*>(&XPp[(size_t)(s0 - 2) * D_DIM + d0]);
        bf16x8 b1v = *reinterpret_cast<const bf16x8*>(&Bp [(size_t)(s0 - 1) * D_DIM + d0]);
        bf16x8 x1v = *reinterpret_cast<const bf16x8*>(&XPp[(size_t)(s0 - 1) * D_DIM + d0]);
        #pragma unroll
        for (int j = 0; j < 8; ++j) {
            p2[j] = b2f((unsigned short)b2v[j]) * b2f((unsigned short)x2v[j]);
            p1[j] = b2f((unsigned short)b1v[j]) * b2f((unsigned short)x1v[j]);
        }
    } else {
        #pragma unroll
        for (int j = 0; j < 8; ++j) {
            p2[j] = state[(d0 + j) * 2 + 0];
            p1[j] = state[(d0 + j) * 2 + 1];
        }
    }

    for (int s = s0; s < s0 + CONV_CHUNK; ++s) {
        bf16x8 bv = *reinterpret_cast<const bf16x8*>(&Bp [(size_t)s * D_DIM + d0]);
        bf16x8 xv = *reinterpret_cast<const bf16x8*>(&XPp[(size_t)s * D_DIM + d0]);
        bf16x8 cv = *reinterpret_cast<const bf16x8*>(&Cp [(size_t)s * D_DIM + d0]);
        bf16x8 o;
        #pragma unroll
        for (int j = 0; j < 8; ++j) {
            float cur = b2f((unsigned short)bv[j]) * b2f((unsigned short)xv[j]);
            float co  = w0[j] * p2[j] + w1[j] * p1[j] + w2[j] * cur;
            o[j] = (short)f2b(b2f((unsigned short)cv[j]) * co);
            p2[j] = p1[j];
            p1[j] = cur;
        }
        *reinterpret_cast<bf16x8*>(&y[(size_t)s * D_DIM + d0]) = o;
    }
}

// ---------------- launch ----------------
extern "C" void kernel_launch(void* const* d_in, const int* in_sizes, int n_in,
                              void* d_out, int out_size, void* d_ws, size_t ws_size,
                              hipStream_t stream) {
    const float* x          = (const float*)d_in[0];
    const float* B_w        = (const float*)d_in[1];
    const float* C_w        = (const float*)d_in[2];
    const float* x_w        = (const float*)d_in[3];
    const float* out_w      = (const float*)d_in[4];
    const float* conv_w     = (const float*)d_in[5];
    const float* conv_state = (const float*)d_in[6];

    const size_t SD = (size_t)S_SEQ * D_DIM;
    const size_t DD = (size_t)D_DIM * D_DIM;

    unsigned short* ws   = (unsigned short*)d_ws;
    unsigned short* xb   = ws;            // SD (x bf16; later reused as y)
    unsigned short* bwb  = xb + SD;       // DD  -- 4 weight buffers contiguous
    unsigned short* cwb  = bwb + DD;
    unsigned short* xwb  = cwb + DD;
    unsigned short* owb  = xwb + DD;
    unsigned short* bx   = owb + DD;      // SD (B projection)
    unsigned short* cbuf = bx + SD;       // SD (C projection)
    unsigned short* xpb  = (unsigned short*)d_out;  // xp scratch, consumed pre-final-GEMM
    unsigned short* yb   = xb;

    // allow 128 KiB dynamic LDS (ignore error; ROCm generally permits directly)
    void* f0 = (void*)gemm_bt<0>;
    void* f2 = (void*)gemm_bt<2>;
    (void)hipFuncSetAttribute(f0, hipFuncAttributeMaxDynamicSharedMemorySize, GEMM_LDS_BYTES);
    (void)hipFuncSetAttribute(f2, hipFuncAttributeMaxDynamicSharedMemorySize, GEMM_LDS_BYTES);

    cast_f32_to_bf16<<<2048, 256, 0, stream>>>(x, xb, (int)(SD / 4));
    dim3 cg(512, 4);
    cast4_f32_to_bf16<<<cg, 256, 0, stream>>>(B_w, C_w, x_w, out_w, bwb, (int)(DD / 4));

    const int nblk = (S_SEQ / 256) * (D_DIM / 256);   // 32*8 = 256
    // B  = x @ B_w^T
    gemm_bt<0><<<nblk, 512, GEMM_LDS_BYTES, stream>>>(xb, bwb, bx,   S_SEQ, D_DIM, D_DIM);
    // xp = x @ x_w^T (into d_out scratch)
    gemm_bt<0><<<nblk, 512, GEMM_LDS_BYTES, stream>>>(xb, xwb, xpb,  S_SEQ, D_DIM, D_DIM);
    // C  = x @ C_w^T
    gemm_bt<0><<<nblk, 512, GEMM_LDS_BYTES, stream>>>(xb, cwb, cbuf, S_SEQ, D_DIM, D_DIM);

    // y = C * conv(B .* xp)   (overwrites xb)
    conv_gate<<<S_SEQ / CONV_CHUNK, 256, 0, stream>>>(bx, xpb, cbuf, conv_w, conv_state, yb);

    // out = y @ out_w^T (fp32)
    gemm_bt<2><<<nblk, 512, GEMM_LDS_BYTES, stream>>>(yb, owb, d_out, S_SEQ, D_DIM, D_DIM);
}